// Round 12
// baseline (461.058 us; speedup 1.0000x reference)
//
#include <hip/hip_runtime.h>
#include <hip/hip_fp16.h>
#include <math.h>

// Graph TransformerConv ×2 on MI355X. N=100k, E=800k, D=64, H=4, C=64.
//
// R12: GEMM restructured to ONE kernel per layer, no LDS: block = 64 nodes
// x all 4 mats; each wave preloads its channel-quarter's B-frags (Q,K,V,S)
// + biases into registers (26+13 loads, L2-hot), then 4 node-groups x 13
// MFMA-pairs with direct stores. Weight-load instrs 800k (R9) -> 163k;
// Xb read once; zero barriers; dispatches 11 -> 9. K,V merged into one
// 512-B row per node (attn: single base addr/edge). Attn math unchanged
// (int8 Q/K sdot4 + fp8 V, split-wave edge pairs, no-max softmax).
// Workspace ~130 MB (guarded).

typedef __attribute__((ext_vector_type(8))) short bf16x8;
typedef __attribute__((ext_vector_type(4))) float f32x4;
typedef __attribute__((ext_vector_type(2))) float f32x2;

#define QKSCALE 32.0f
// logit = idot / (32*32*8); w = exp(logit) = exp2(idot * log2e/8192)
#define C_EXP2 1.760325e-4f

__device__ inline unsigned short f2bf(float f) {
    unsigned int u = __float_as_uint(f);
    u = (u + 0x7fffu + ((u >> 16) & 1u)) >> 16;
    return (unsigned short)u;
}

// ---------------- fp8 e4m3 pack/unpack (HW on gfx950) ----------------
#if __has_builtin(__builtin_amdgcn_cvt_pk_fp8_f32) && __has_builtin(__builtin_amdgcn_cvt_pk_f32_fp8)
#define HW_FP8 1
#endif

#ifndef HW_FP8
__device__ inline unsigned int fp8_enc1(float f) {
    unsigned int u = __float_as_uint(f);
    unsigned int s = (u >> 24) & 0x80u;
    float a = fabsf(f);
    if (a >= 448.f) return s | 0x7Eu;
    if (a < 0.015625f) return s;
    unsigned int ua = __float_as_uint(a);
    unsigned int r = ua + 0x7FFFFu + ((ua >> 20) & 1u);
    int e = (int)((r >> 23) & 255u) - 120;
    unsigned int m = (r >> 20) & 7u;
    if (e < 1) return s;
    if (e > 15) return s | 0x7Eu;
    return s | (unsigned int)((e << 3) | m);
}
__device__ inline float fp8_dec1(unsigned int b) {
    unsigned int e = (b >> 3) & 15u, m = b & 7u;
    float v;
    if (e) v = __uint_as_float(((e + 120u) << 23) | (m << 20));
    else   v = (float)m * 0.001953125f;
    return (b & 0x80u) ? -v : v;
}
#endif

__device__ inline unsigned int fp8x4_pack(float f0, float f1, float f2, float f3) {
#ifdef HW_FP8
    int pk = __builtin_amdgcn_cvt_pk_fp8_f32(f0, f1, 0, false);
    pk = __builtin_amdgcn_cvt_pk_fp8_f32(f2, f3, pk, true);
    return (unsigned int)pk;
#else
    return fp8_enc1(f0) | (fp8_enc1(f1) << 8) | (fp8_enc1(f2) << 16) | (fp8_enc1(f3) << 24);
#endif
}

__device__ inline float4 fp8x4_unpack(unsigned int k) {
#ifdef HW_FP8
    f32x2 lo = __builtin_amdgcn_cvt_pk_f32_fp8((int)k, false);
    f32x2 hi = __builtin_amdgcn_cvt_pk_f32_fp8((int)k, true);
    return make_float4(lo[0], lo[1], hi[0], hi[1]);
#else
    return make_float4(fp8_dec1(k & 255u), fp8_dec1((k >> 8) & 255u),
                       fp8_dec1((k >> 16) & 255u), fp8_dec1(k >> 24));
#endif
}

// ---------------- int8 pack / sdot4 ----------------
__device__ inline unsigned int i8x4_pack(float f0, float f1, float f2, float f3) {
    int a = (int)rintf(f0 * QKSCALE); a = a < -127 ? -127 : (a > 127 ? 127 : a);
    int b = (int)rintf(f1 * QKSCALE); b = b < -127 ? -127 : (b > 127 ? 127 : b);
    int c = (int)rintf(f2 * QKSCALE); c = c < -127 ? -127 : (c > 127 ? 127 : c);
    int d = (int)rintf(f3 * QKSCALE); d = d < -127 ? -127 : (d > 127 ? 127 : d);
    return (unsigned int)((a & 255) | ((b & 255) << 8) | ((c & 255) << 16) | ((d & 255) << 24));
}

__device__ inline int sdot4(unsigned int a, unsigned int b, int c) {
#if __has_builtin(__builtin_amdgcn_sdot4)
    return __builtin_amdgcn_sdot4((int)a, (int)b, c, false);
#else
    int r = c;
#pragma unroll
    for (int i = 0; i < 4; ++i) {
        int ai = (int)(a << (24 - 8 * i)) >> 24;
        int bi = (int)(b << (24 - 8 * i)) >> 24;
        r += ai * bi;
    }
    return r;
#endif
}

// ---------------- setup: X cast + weight prep (both layers) + CSR zero -----
__global__ void k_setup(
    const float* __restrict__ x, unsigned short* __restrict__ Xb, int ncast4,
    const float* __restrict__ Wq1, const float* __restrict__ Wk1,
    const float* __restrict__ Wv1, const float* __restrict__ Ws1,
    const float* __restrict__ Wq2, const float* __restrict__ Wk2,
    const float* __restrict__ Wv2, const float* __restrict__ Ws2,
    unsigned short* __restrict__ Wt,
    int* __restrict__ counts, int* __restrict__ cursor, int N, int castBl)
{
    int b = blockIdx.x, tid = threadIdx.x;
    if (b < castBl) {
        int i = b * 256 + tid;
        if (i < ncast4) {
            float4 v = ((const float4*)x)[i];
            ushort4 o;
            o.x = f2bf(v.x); o.y = f2bf(v.y); o.z = f2bf(v.z); o.w = f2bf(v.w);
            ((ushort4*)Xb)[i] = o;
        }
    } else if (b < castBl + 416) {
        int j = (b - castBl) * 256 + tid;   // < 106496
        int layer = j / 53248;
        int r = j % 53248;
        if (r < 49152) {
            int m = r / 16384, w = r % 16384;
            int n = w / 64, k = w % 64;
            const float* W = (layer == 0)
                ? ((m == 0) ? Wq1 : (m == 1) ? Wk1 : Wv1)
                : ((m == 0) ? Wq2 : (m == 1) ? Wk2 : Wv2);
            Wt[layer * 53248 + m * 16384 + n * 64 + k] = f2bf(W[k * 256 + n]);
        } else {
            int w = r - 49152;
            int n = w / 64, k = w % 64;
            const float* W = (layer == 0) ? Ws1 : Ws2;
            Wt[layer * 53248 + 49152 + n * 64 + k] = f2bf(W[k * 64 + n]);
        }
    } else {
        int i = (b - castBl - 416) * 256 + tid;
        if (i < N) { counts[i] = 0; cursor[i] = 0; }
    }
}

// ---------------- CSR build ----------------
__global__ void k_hist(const int* __restrict__ dst, int E, int* __restrict__ counts) {
    int e = blockIdx.x * 256 + threadIdx.x;
    if (e < E) atomicAdd(&counts[dst[e]], 1);
}

#define SCAN_B 256
#define SCAN_CHUNK 2048
__global__ void k_scan1(const int* __restrict__ counts, int n,
                        int* __restrict__ offs, int* __restrict__ bsums) {
    __shared__ int lds[SCAN_B];
    int b = blockIdx.x, tid = threadIdx.x;
    int base = b * SCAN_CHUNK + tid * 8;
    int v[8]; int s = 0;
#pragma unroll
    for (int i = 0; i < 8; ++i) { int idx = base + i; int c = (idx < n) ? counts[idx] : 0; v[i] = s; s += c; }
    lds[tid] = s;
    for (int off = 1; off < SCAN_B; off <<= 1) {
        __syncthreads();
        int x = (tid >= off) ? lds[tid - off] : 0;
        __syncthreads();
        lds[tid] += x;
    }
    __syncthreads();
    int texcl = lds[tid] - s;
#pragma unroll
    for (int i = 0; i < 8; ++i) { int idx = base + i; if (idx < n) offs[idx] = texcl + v[i]; }
    if (tid == SCAN_B - 1) bsums[b] = lds[tid];
}

__global__ void k_scan2(int* bsums, int nb) {
    __shared__ int lds[256];
    int t = threadIdx.x;
    if (nb > 256) {
        if (t == 0) { int s = 0; for (int i = 0; i < nb; ++i) { int c = bsums[i]; bsums[i] = s; s += c; } }
        return;
    }
    int v = (t < nb) ? bsums[t] : 0;
    lds[t] = v;
    for (int off = 1; off < 256; off <<= 1) {
        __syncthreads();
        int x = (t >= off) ? lds[t - off] : 0;
        __syncthreads();
        lds[t] += x;
    }
    __syncthreads();
    if (t < nb) bsums[t] = lds[t] - v;   // exclusive
}

__global__ void k_scatter(const int* __restrict__ src, const int* __restrict__ dst, int E,
                          const int* __restrict__ offs, const int* __restrict__ bsums,
                          int* __restrict__ cursor, int* __restrict__ csr_src) {
    int e = blockIdx.x * 256 + threadIdx.x;
    if (e < E) {
        int d = dst[e];
        int p = offs[d] + bsums[d >> 11] + atomicAdd(&cursor[d], 1);
        csr_src[p] = src[e];
    }
}

// ---------------- fused GEMM: 64 nodes x all 4 mats, no LDS ----------------
// Operand-swapped mfma: D col=node (n16), row=channel (quad*4+reg).
// Wave w owns channel quarter w*64..+63 of Q,K,V and w*16..+15 of S.
// B-frags + biases preloaded to registers; 4 node-groups; direct stores.
// Q int8 [node][256B]; KV row 512 B: K int8 @0, V fp8 @256; S fp32 256 B.
__global__ __launch_bounds__(256) void k_gemm(
    const unsigned short* __restrict__ Xb, int nrows,
    const unsigned short* __restrict__ WtL,
    const float* __restrict__ bqp, const float* __restrict__ bkp,
    const float* __restrict__ bvp, const float* __restrict__ bsp,
    unsigned char* __restrict__ Qb, unsigned char* __restrict__ KVb,
    unsigned char* __restrict__ Sb)
{
    int tid = threadIdx.x;
    int wave = tid >> 6, lane = tid & 63;
    int quad = lane >> 4, n16 = lane & 15;
    int r0 = blockIdx.x * 64;

    const unsigned short* Wq = WtL;
    const unsigned short* Wk = WtL + 16384;
    const unsigned short* Wv = WtL + 32768;
    const unsigned short* Ws = WtL + 49152;

    bf16x8 fQ[8], fK[8], fV[8], fS[2];
    float4 cQ[4], cK[4], cV[4], cS;
#pragma unroll
    for (int c = 0; c < 4; ++c) {
        int ct = wave * 4 + c;
        int roff = (ct * 16 + n16) * 64 + quad * 8;
        fQ[2 * c]     = *(const bf16x8*)(Wq + roff);
        fQ[2 * c + 1] = *(const bf16x8*)(Wq + roff + 32);
        fK[2 * c]     = *(const bf16x8*)(Wk + roff);
        fK[2 * c + 1] = *(const bf16x8*)(Wk + roff + 32);
        fV[2 * c]     = *(const bf16x8*)(Wv + roff);
        fV[2 * c + 1] = *(const bf16x8*)(Wv + roff + 32);
        cQ[c] = *(const float4*)(bqp + ct * 16 + quad * 4);
        cK[c] = *(const float4*)(bkp + ct * 16 + quad * 4);
        cV[c] = *(const float4*)(bvp + ct * 16 + quad * 4);
    }
    {
        int roff = (wave * 16 + n16) * 64 + quad * 8;
        fS[0] = *(const bf16x8*)(Ws + roff);
        fS[1] = *(const bf16x8*)(Ws + roff + 32);
        cS = *(const float4*)(bsp + wave * 16 + quad * 4);
    }

#pragma unroll
    for (int g = 0; g < 4; ++g) {
        int node = r0 + g * 16 + n16;
        int nodec = (node < nrows) ? node : (nrows - 1);
        bf16x8 a0 = *(const bf16x8*)(Xb + (size_t)nodec * 64 + quad * 8);
        bf16x8 a1 = *(const bf16x8*)(Xb + (size_t)nodec * 64 + 32 + quad * 8);
        bool ok = node < nrows;
#pragma unroll
        for (int c = 0; c < 4; ++c) {
            int ch0 = (wave * 4 + c) * 16 + quad * 4;
            f32x4 aq = {0.f, 0.f, 0.f, 0.f};
            aq = __builtin_amdgcn_mfma_f32_16x16x32_bf16(fQ[2 * c], a0, aq, 0, 0, 0);
            aq = __builtin_amdgcn_mfma_f32_16x16x32_bf16(fQ[2 * c + 1], a1, aq, 0, 0, 0);
            f32x4 ak = {0.f, 0.f, 0.f, 0.f};
            ak = __builtin_amdgcn_mfma_f32_16x16x32_bf16(fK[2 * c], a0, ak, 0, 0, 0);
            ak = __builtin_amdgcn_mfma_f32_16x16x32_bf16(fK[2 * c + 1], a1, ak, 0, 0, 0);
            f32x4 av = {0.f, 0.f, 0.f, 0.f};
            av = __builtin_amdgcn_mfma_f32_16x16x32_bf16(fV[2 * c], a0, av, 0, 0, 0);
            av = __builtin_amdgcn_mfma_f32_16x16x32_bf16(fV[2 * c + 1], a1, av, 0, 0, 0);
            if (ok) {
                *(unsigned int*)(Qb + (size_t)node * 256 + ch0) =
                    i8x4_pack(aq[0] + cQ[c].x, aq[1] + cQ[c].y, aq[2] + cQ[c].z, aq[3] + cQ[c].w);
                *(unsigned int*)(KVb + (size_t)node * 512 + ch0) =
                    i8x4_pack(ak[0] + cK[c].x, ak[1] + cK[c].y, ak[2] + cK[c].z, ak[3] + cK[c].w);
                *(unsigned int*)(KVb + (size_t)node * 512 + 256 + ch0) =
                    fp8x4_pack(av[0] + cV[c].x, av[1] + cV[c].y, av[2] + cV[c].z, av[3] + cV[c].w);
            }
        }
        {
            int ch0 = wave * 16 + quad * 4;
            f32x4 as = {0.f, 0.f, 0.f, 0.f};
            as = __builtin_amdgcn_mfma_f32_16x16x32_bf16(fS[0], a0, as, 0, 0, 0);
            as = __builtin_amdgcn_mfma_f32_16x16x32_bf16(fS[1], a1, as, 0, 0, 0);
            if (ok)
                *(float4*)(Sb + (size_t)node * 256 + ch0 * 4) =
                    make_float4(as[0] + cS.x, as[1] + cS.y, as[2] + cS.z, as[3] + cS.w);
        }
    }
}

// ---------------- Attention: split-wave edge pairs, int8 dot ---------------
__global__ __launch_bounds__(256) void k_attn(
    const unsigned char* __restrict__ Qb, const unsigned char* __restrict__ KVb,
    const unsigned char* __restrict__ Sb,
    const int* __restrict__ offs, const int* __restrict__ bsums,
    const int* __restrict__ csr_src,
    float* __restrict__ out, unsigned short* __restrict__ Xb,
    int n, int Etot, int mode)
{
    int node = blockIdx.x * 4 + (threadIdx.x >> 6);
    if (node >= n) return;
    int lane = threadIdx.x & 63;
    int sl = lane & 31;
    int half = lane >> 5;
    uint2 q8 = *(const uint2*)(Qb + (size_t)node * 256 + sl * 8);
    int beg = offs[node] + bsums[node >> 11];
    int end = (node + 1 < n) ? (offs[node + 1] + bsums[(node + 1) >> 11]) : Etot;
    float l = 0.f;
    float acc[8];
#pragma unroll
    for (int i = 0; i < 8; ++i) acc[i] = 0.f;
    for (int base = beg; base < end; base += 8) {
        int cnt = end - base; if (cnt > 8) cnt = 8;
        int my = (lane < cnt) ? csr_src[base + lane] : 0;
        uint2 kk[4], vv[4];
#pragma unroll
        for (int p = 0; p < 4; ++p) {
            int idx = __shfl(my, 2 * p + half);
            const unsigned char* row = KVb + (size_t)idx * 512 + sl * 8;
            kk[p] = *(const uint2*)(row);
            vv[p] = *(const uint2*)(row + 256);
        }
#pragma unroll
        for (int p = 0; p < 4; ++p) {
            int d = sdot4(kk[p].x, q8.x, 0);
            d = sdot4(kk[p].y, q8.y, d);
            d += __shfl_xor(d, 1); d += __shfl_xor(d, 2); d += __shfl_xor(d, 4);
            float w = __builtin_exp2f((float)d * C_EXP2);
            w = (2 * p + half < cnt) ? w : 0.f;
            l += w;
            float4 va = fp8x4_unpack(vv[p].x);
            float4 vb = fp8x4_unpack(vv[p].y);
            acc[0] += va.x * w; acc[1] += va.y * w;
            acc[2] += va.z * w; acc[3] += va.w * w;
            acc[4] += vb.x * w; acc[5] += vb.y * w;
            acc[6] += vb.z * w; acc[7] += vb.w * w;
        }
    }
    l += __shfl_xor(l, 32);
#pragma unroll
    for (int i = 0; i < 8; ++i) acc[i] += __shfl_xor(acc[i], 32);
    float inv = 1.f / (l + 1e-16f);
#pragma unroll
    for (int i = 0; i < 8; ++i) acc[i] *= inv;
#pragma unroll
    for (int i = 0; i < 8; ++i) {
        acc[i] += __shfl_xor(acc[i], 8);
        acc[i] += __shfl_xor(acc[i], 16);
        acc[i] *= 0.25f;
    }
    if (lane < 8) {
        const float* Srow = (const float*)(Sb + (size_t)node * 256);
        float4 s0 = *(const float4*)(Srow + lane * 8);
        float4 s1 = *(const float4*)(Srow + lane * 8 + 4);
        float r0 = acc[0] + s0.x, r1 = acc[1] + s0.y;
        float r2 = acc[2] + s0.z, r3 = acc[3] + s0.w;
        float r4 = acc[4] + s1.x, r5 = acc[5] + s1.y;
        float r6 = acc[6] + s1.z, r7 = acc[7] + s1.w;
        if (mode == 1) {
            r0 = fmaxf(r0, 0.f); r1 = fmaxf(r1, 0.f);
            r2 = fmaxf(r2, 0.f); r3 = fmaxf(r3, 0.f);
            r4 = fmaxf(r4, 0.f); r5 = fmaxf(r5, 0.f);
            r6 = fmaxf(r6, 0.f); r7 = fmaxf(r7, 0.f);
            uint4 o;
            o.x = (unsigned int)f2bf(r0) | ((unsigned int)f2bf(r1) << 16);
            o.y = (unsigned int)f2bf(r2) | ((unsigned int)f2bf(r3) << 16);
            o.z = (unsigned int)f2bf(r4) | ((unsigned int)f2bf(r5) << 16);
            o.w = (unsigned int)f2bf(r6) | ((unsigned int)f2bf(r7) << 16);
            *(uint4*)(Xb + (size_t)node * 64 + lane * 8) = o;
        } else {
            *(float4*)(out + (size_t)node * 64 + lane * 8) = make_float4(r0, r1, r2, r3);
            *(float4*)(out + (size_t)node * 64 + lane * 8 + 4) = make_float4(r4, r5, r6, r7);
        }
    }
}

extern "C" void kernel_launch(void* const* d_in, const int* in_sizes, int n_in,
                              void* d_out, int out_size, void* d_ws, size_t ws_size,
                              hipStream_t stream)
{
    const float* x  = (const float*)d_in[0];
    const int*   ei = (const int*)d_in[1];
    int N = in_sizes[0] / 64;
    int E = in_sizes[1] / 2;
    const int* srcp = ei;
    const int* dstp = ei + E;
    const float* Wq1 = (const float*)d_in[2],  *bq1 = (const float*)d_in[3];
    const float* Wk1 = (const float*)d_in[4],  *bk1 = (const float*)d_in[5];
    const float* Wv1 = (const float*)d_in[6],  *bv1 = (const float*)d_in[7];
    const float* Ws1 = (const float*)d_in[8],  *bs1 = (const float*)d_in[9];
    const float* Wq2 = (const float*)d_in[10], *bq2 = (const float*)d_in[11];
    const float* Wk2 = (const float*)d_in[12], *bk2 = (const float*)d_in[13];
    const float* Wv2 = (const float*)d_in[14], *bv2 = (const float*)d_in[15];
    const float* Ws2 = (const float*)d_in[16], *bs2 = (const float*)d_in[17];
    float* out = (float*)d_out;

    // workspace layout (~130 MB)
    char* ws = (char*)d_ws;
    size_t off = 0;
    auto alloc = [&](size_t bytes) -> void* {
        void* p = ws + off;
        off = (off + bytes + 255) & ~(size_t)255;
        return p;
    };
    unsigned short* Xb = (unsigned short*)alloc((size_t)N * 64 * 2);
    unsigned char* Qb  = (unsigned char*)alloc(((size_t)N + 64) * 256);
    unsigned char* KVb = (unsigned char*)alloc(((size_t)N + 64) * 512);
    unsigned char* Sb  = (unsigned char*)alloc(((size_t)N + 64) * 256);
    unsigned short* Wt = (unsigned short*)alloc(2 * 53248 * 2);
    int* counts = (int*)alloc((size_t)N * 4);
    int* cursor = (int*)alloc((size_t)N * 4);
    int* offs   = (int*)alloc((size_t)N * 4);
    int* bsums  = (int*)alloc(1024 * 4);
    int* csr    = (int*)alloc((size_t)E * 4);
    (void)n_in; (void)out_size;
    if (off > ws_size) return;  // diagnostic: too-small ws -> zeros, not a fault

    int ebl = (E + 255) / 256;
    int nb_scan = (N + SCAN_CHUNK - 1) / SCAN_CHUNK;
    int row_bl = (N + 63) / 64;
    int attn_bl = (N + 3) / 4;
    int ncast4 = N * 16;
    int castBl = (ncast4 + 255) / 256;
    int zeroBl = (N + 255) / 256;

    k_setup<<<castBl + 416 + zeroBl, 256, 0, stream>>>(
        x, Xb, ncast4, Wq1, Wk1, Wv1, Ws1, Wq2, Wk2, Wv2, Ws2, Wt,
        counts, cursor, N, castBl);

    k_hist<<<ebl, 256, 0, stream>>>(dstp, E, counts);
    k_scan1<<<nb_scan, SCAN_B, 0, stream>>>(counts, N, offs, bsums);
    k_scan2<<<1, 256, 0, stream>>>(bsums, nb_scan);
    k_scatter<<<ebl, 256, 0, stream>>>(srcp, dstp, E, offs, bsums, cursor, csr);

    // ---- layer 1 (h1 -> Xb bf16 directly) ----
    k_gemm<<<row_bl, 256, 0, stream>>>(Xb, N, Wt, bq1, bk1, bv1, bs1, Qb, KVb, Sb);
    k_attn<<<attn_bl, 256, 0, stream>>>(Qb, KVb, Sb, offs, bsums, csr, out, Xb, N, E, 1);

    // ---- layer 2 ----
    k_gemm<<<row_bl, 256, 0, stream>>>(Xb, N, Wt + 53248, bq2, bk2, bv2, bs2, Qb, KVb, Sb);
    k_attn<<<attn_bl, 256, 0, stream>>>(Qb, KVb, Sb, offs, bsums, csr, out, Xb, N, E, 0);
}

// Round 13
// 395.375 us; speedup vs baseline: 1.1661x; 1.1661x over previous
//
#include <hip/hip_runtime.h>
#include <hip/hip_fp16.h>
#include <math.h>

// Graph TransformerConv ×2 on MI355X. N=100k, E=800k, D=64, H=4, C=64.
//
// R13: GEMM = R12's register-preloaded weights (no redundant reads) + R9's
// wave-private LDS store transpose (no partial-line stores): per mat,
// 16 ds_writes -> 4 ds_read_b128 -> 4 dwordx4 stores of 16 FULL 64-B lines.
// CSR: hist stores rank[e] (one atomic pass); scatter is atomic-free; hist
// fused into the layer-1 GEMM dispatch (independent, block-range split).
// 8 dispatches. Attn unchanged (int8 sdot4 + fp8 V, split-wave, no-max).
// Workspace ~133 MB (guarded).

typedef __attribute__((ext_vector_type(8))) short bf16x8;
typedef __attribute__((ext_vector_type(4))) float f32x4;
typedef __attribute__((ext_vector_type(2))) float f32x2;

#define QKSCALE 32.0f
#define C_EXP2 1.760325e-4f   // log2e / (32*32*8)

__device__ inline unsigned short f2bf(float f) {
    unsigned int u = __float_as_uint(f);
    u = (u + 0x7fffu + ((u >> 16) & 1u)) >> 16;
    return (unsigned short)u;
}

#if __has_builtin(__builtin_amdgcn_cvt_pk_fp8_f32) && __has_builtin(__builtin_amdgcn_cvt_pk_f32_fp8)
#define HW_FP8 1
#endif

#ifndef HW_FP8
__device__ inline unsigned int fp8_enc1(float f) {
    unsigned int u = __float_as_uint(f);
    unsigned int s = (u >> 24) & 0x80u;
    float a = fabsf(f);
    if (a >= 448.f) return s | 0x7Eu;
    if (a < 0.015625f) return s;
    unsigned int ua = __float_as_uint(a);
    unsigned int r = ua + 0x7FFFFu + ((ua >> 20) & 1u);
    int e = (int)((r >> 23) & 255u) - 120;
    unsigned int m = (r >> 20) & 7u;
    if (e < 1) return s;
    if (e > 15) return s | 0x7Eu;
    return s | (unsigned int)((e << 3) | m);
}
__device__ inline float fp8_dec1(unsigned int b) {
    unsigned int e = (b >> 3) & 15u, m = b & 7u;
    float v;
    if (e) v = __uint_as_float(((e + 120u) << 23) | (m << 20));
    else   v = (float)m * 0.001953125f;
    return (b & 0x80u) ? -v : v;
}
#endif

__device__ inline unsigned int fp8x4_pack(float f0, float f1, float f2, float f3) {
#ifdef HW_FP8
    int pk = __builtin_amdgcn_cvt_pk_fp8_f32(f0, f1, 0, false);
    pk = __builtin_amdgcn_cvt_pk_fp8_f32(f2, f3, pk, true);
    return (unsigned int)pk;
#else
    return fp8_enc1(f0) | (fp8_enc1(f1) << 8) | (fp8_enc1(f2) << 16) | (fp8_enc1(f3) << 24);
#endif
}

__device__ inline float4 fp8x4_unpack(unsigned int k) {
#ifdef HW_FP8
    f32x2 lo = __builtin_amdgcn_cvt_pk_f32_fp8((int)k, false);
    f32x2 hi = __builtin_amdgcn_cvt_pk_f32_fp8((int)k, true);
    return make_float4(lo[0], lo[1], hi[0], hi[1]);
#else
    return make_float4(fp8_dec1(k & 255u), fp8_dec1((k >> 8) & 255u),
                       fp8_dec1((k >> 16) & 255u), fp8_dec1(k >> 24));
#endif
}

__device__ inline unsigned int i8x4_pack(float f0, float f1, float f2, float f3) {
    int a = (int)rintf(f0 * QKSCALE); a = a < -127 ? -127 : (a > 127 ? 127 : a);
    int b = (int)rintf(f1 * QKSCALE); b = b < -127 ? -127 : (b > 127 ? 127 : b);
    int c = (int)rintf(f2 * QKSCALE); c = c < -127 ? -127 : (c > 127 ? 127 : c);
    int d = (int)rintf(f3 * QKSCALE); d = d < -127 ? -127 : (d > 127 ? 127 : d);
    return (unsigned int)((a & 255) | ((b & 255) << 8) | ((c & 255) << 16) | ((d & 255) << 24));
}

__device__ inline int sdot4(unsigned int a, unsigned int b, int c) {
#if __has_builtin(__builtin_amdgcn_sdot4)
    return __builtin_amdgcn_sdot4((int)a, (int)b, c, false);
#else
    int r = c;
#pragma unroll
    for (int i = 0; i < 4; ++i) {
        int ai = (int)(a << (24 - 8 * i)) >> 24;
        int bi = (int)(b << (24 - 8 * i)) >> 24;
        r += ai * bi;
    }
    return r;
#endif
}

// ---------------- setup: X cast + weight prep (both layers) + CSR zero -----
__global__ void k_setup(
    const float* __restrict__ x, unsigned short* __restrict__ Xb, int ncast4,
    const float* __restrict__ Wq1, const float* __restrict__ Wk1,
    const float* __restrict__ Wv1, const float* __restrict__ Ws1,
    const float* __restrict__ Wq2, const float* __restrict__ Wk2,
    const float* __restrict__ Wv2, const float* __restrict__ Ws2,
    unsigned short* __restrict__ Wt,
    int* __restrict__ counts, int N, int castBl)
{
    int b = blockIdx.x, tid = threadIdx.x;
    if (b < castBl) {
        int i = b * 256 + tid;
        if (i < ncast4) {
            float4 v = ((const float4*)x)[i];
            ushort4 o;
            o.x = f2bf(v.x); o.y = f2bf(v.y); o.z = f2bf(v.z); o.w = f2bf(v.w);
            ((ushort4*)Xb)[i] = o;
        }
    } else if (b < castBl + 416) {
        int j = (b - castBl) * 256 + tid;   // < 106496
        int layer = j / 53248;
        int r = j % 53248;
        if (r < 49152) {
            int m = r / 16384, w = r % 16384;
            int n = w / 64, k = w % 64;
            const float* W = (layer == 0)
                ? ((m == 0) ? Wq1 : (m == 1) ? Wk1 : Wv1)
                : ((m == 0) ? Wq2 : (m == 1) ? Wk2 : Wv2);
            Wt[layer * 53248 + m * 16384 + n * 64 + k] = f2bf(W[k * 256 + n]);
        } else {
            int w = r - 49152;
            int n = w / 64, k = w % 64;
            const float* W = (layer == 0) ? Ws1 : Ws2;
            Wt[layer * 53248 + 49152 + n * 64 + k] = f2bf(W[k * 64 + n]);
        }
    } else {
        int i = (b - castBl - 416) * 256 + tid;
        if (i < N) counts[i] = 0;
    }
}

// ---------------- CSR scan ----------------
#define SCAN_B 256
#define SCAN_CHUNK 2048
__global__ void k_scan1(const int* __restrict__ counts, int n,
                        int* __restrict__ offs, int* __restrict__ bsums) {
    __shared__ int lds[SCAN_B];
    int b = blockIdx.x, tid = threadIdx.x;
    int base = b * SCAN_CHUNK + tid * 8;
    int v[8]; int s = 0;
#pragma unroll
    for (int i = 0; i < 8; ++i) { int idx = base + i; int c = (idx < n) ? counts[idx] : 0; v[i] = s; s += c; }
    lds[tid] = s;
    for (int off = 1; off < SCAN_B; off <<= 1) {
        __syncthreads();
        int x = (tid >= off) ? lds[tid - off] : 0;
        __syncthreads();
        lds[tid] += x;
    }
    __syncthreads();
    int texcl = lds[tid] - s;
#pragma unroll
    for (int i = 0; i < 8; ++i) { int idx = base + i; if (idx < n) offs[idx] = texcl + v[i]; }
    if (tid == SCAN_B - 1) bsums[b] = lds[tid];
}

__global__ void k_scan2(int* bsums, int nb) {
    __shared__ int lds[256];
    int t = threadIdx.x;
    if (nb > 256) {
        if (t == 0) { int s = 0; for (int i = 0; i < nb; ++i) { int c = bsums[i]; bsums[i] = s; s += c; } }
        return;
    }
    int v = (t < nb) ? bsums[t] : 0;
    lds[t] = v;
    for (int off = 1; off < 256; off <<= 1) {
        __syncthreads();
        int x = (t >= off) ? lds[t - off] : 0;
        __syncthreads();
        lds[t] += x;
    }
    __syncthreads();
    if (t < nb) bsums[t] = lds[t] - v;   // exclusive
}

// atomic-free scatter using per-edge rank from the hist pass
__global__ void k_scatter(const int* __restrict__ src, const int* __restrict__ dst, int E,
                          const int* __restrict__ offs, const int* __restrict__ bsums,
                          const int* __restrict__ rank, int* __restrict__ csr_src) {
    int e = blockIdx.x * 256 + threadIdx.x;
    if (e < E) {
        int d = dst[e];
        csr_src[offs[d] + bsums[d >> 11] + rank[e]] = src[e];
    }
}

// ---------------- fused GEMM (+hist blocks): register weights, LDS-dense stores
// Block = 64 nodes x all 4 mats. Wave w owns channel quarter w*64..+63 B of
// each output row. Per mat: 16 ds_write_b32 (wave-private tile, stride 68:
// 2-way-free banks) -> 4x {ds_read_b128 + dwordx4 store of 16 FULL lines}.
// Q int8 [node][256B]; KV 512 B/row: K int8 @0, V fp8 @256; S fp32 256 B.
#define GST 68
__global__ __launch_bounds__(256) void k_gemm(
    const unsigned short* __restrict__ Xb, int nrows,
    const unsigned short* __restrict__ WtL,
    const float* __restrict__ bqp, const float* __restrict__ bkp,
    const float* __restrict__ bvp, const float* __restrict__ bsp,
    unsigned char* __restrict__ Qb, unsigned char* __restrict__ KVb,
    unsigned char* __restrict__ Sb,
    const int* __restrict__ dstp, int histE,
    int* __restrict__ counts, int* __restrict__ rank, int gemmBl)
{
    __shared__ unsigned char st[4 * 64 * GST];   // 17408 B
    int tid = threadIdx.x;
    if (blockIdx.x >= gemmBl) {                  // ---- hist blocks ----
        int e = (blockIdx.x - gemmBl) * 256 + tid;
        if (e < histE) rank[e] = atomicAdd(&counts[dstp[e]], 1);
        return;
    }
    int wave = tid >> 6, lane = tid & 63;
    int quad = lane >> 4, n16 = lane & 15;
    int r0 = blockIdx.x * 64;
    unsigned char* wst = st + wave * 64 * GST;

    const unsigned short* Wq = WtL;
    const unsigned short* Wk = WtL + 16384;
    const unsigned short* Wv = WtL + 32768;
    const unsigned short* Ws = WtL + 49152;

    bf16x8 fQ[8], fK[8], fV[8], fS[2];
    float4 cQ[4], cK[4], cV[4], cS;
#pragma unroll
    for (int c = 0; c < 4; ++c) {
        int ct = wave * 4 + c;
        int roff = (ct * 16 + n16) * 64 + quad * 8;
        fQ[2 * c]     = *(const bf16x8*)(Wq + roff);
        fQ[2 * c + 1] = *(const bf16x8*)(Wq + roff + 32);
        fK[2 * c]     = *(const bf16x8*)(Wk + roff);
        fK[2 * c + 1] = *(const bf16x8*)(Wk + roff + 32);
        fV[2 * c]     = *(const bf16x8*)(Wv + roff);
        fV[2 * c + 1] = *(const bf16x8*)(Wv + roff + 32);
        cQ[c] = *(const float4*)(bqp + ct * 16 + quad * 4);
        cK[c] = *(const float4*)(bkp + ct * 16 + quad * 4);
        cV[c] = *(const float4*)(bvp + ct * 16 + quad * 4);
    }
    {
        int roff = (wave * 16 + n16) * 64 + quad * 8;
        fS[0] = *(const bf16x8*)(Ws + roff);
        fS[1] = *(const bf16x8*)(Ws + roff + 32);
        cS = *(const float4*)(bsp + wave * 16 + quad * 4);
    }
    // preload A-fragments for all 4 node groups
    bf16x8 a0[4], a1[4];
#pragma unroll
    for (int g = 0; g < 4; ++g) {
        int node = r0 + g * 16 + n16;
        int nodec = (node < nrows) ? node : (nrows - 1);
        a0[g] = *(const bf16x8*)(Xb + (size_t)nodec * 64 + quad * 8);
        a1[g] = *(const bf16x8*)(Xb + (size_t)nodec * 64 + 32 + quad * 8);
    }

    // ---- helper: stage one 256-ch mat into LDS, flush dense ----
    auto do_mat = [&](const bf16x8* fm, const float4* cm,
                      unsigned char* base, int stride, bool isInt8) {
#pragma unroll
        for (int g = 0; g < 4; ++g) {
#pragma unroll
            for (int c = 0; c < 4; ++c) {
                f32x4 acc = {0.f, 0.f, 0.f, 0.f};
                acc = __builtin_amdgcn_mfma_f32_16x16x32_bf16(fm[2 * c], a0[g], acc, 0, 0, 0);
                acc = __builtin_amdgcn_mfma_f32_16x16x32_bf16(fm[2 * c + 1], a1[g], acc, 0, 0, 0);
                float f0 = acc[0] + cm[c].x, f1 = acc[1] + cm[c].y;
                float f2 = acc[2] + cm[c].z, f3 = acc[3] + cm[c].w;
                unsigned int pk = isInt8 ? i8x4_pack(f0, f1, f2, f3)
                                         : fp8x4_pack(f0, f1, f2, f3);
                *(unsigned int*)(wst + (g * 16 + n16) * GST + c * 16 + quad * 4) = pk;
            }
        }
#pragma unroll
        for (int it = 0; it < 4; ++it) {
            int row = it * 16 + (lane >> 2);
            uint4 v = *(const uint4*)(wst + row * GST + (lane & 3) * 16);
            int node = r0 + row;
            if (node < nrows)
                *(uint4*)(base + (size_t)node * stride + wave * 64 + (lane & 3) * 16) = v;
        }
    };
    do_mat(fQ, cQ, Qb, 256, true);        // Q int8
    do_mat(fK, cK, KVb, 512, true);       // K int8 (bytes [0,256) of KV row)
    do_mat(fV, cV, KVb + 256, 512, false);// V fp8  (bytes [256,512))
    // ---- S (fp32, wave owns 16 ch = 64 B/node) ----
#pragma unroll
    for (int g = 0; g < 4; ++g) {
        f32x4 acc = {0.f, 0.f, 0.f, 0.f};
        acc = __builtin_amdgcn_mfma_f32_16x16x32_bf16(fS[0], a0[g], acc, 0, 0, 0);
        acc = __builtin_amdgcn_mfma_f32_16x16x32_bf16(fS[1], a1[g], acc, 0, 0, 0);
        *(float4*)(wst + (g * 16 + n16) * GST + quad * 16) =
            make_float4(acc[0] + cS.x, acc[1] + cS.y, acc[2] + cS.z, acc[3] + cS.w);
    }
#pragma unroll
    for (int it = 0; it < 4; ++it) {
        int row = it * 16 + (lane >> 2);
        uint4 v = *(const uint4*)(wst + row * GST + (lane & 3) * 16);
        int node = r0 + row;
        if (node < nrows)
            *(uint4*)(Sb + (size_t)node * 256 + wave * 64 + (lane & 3) * 16) = v;
    }
}

// ---------------- Attention: split-wave edge pairs, int8 dot ---------------
__global__ __launch_bounds__(256) void k_attn(
    const unsigned char* __restrict__ Qb, const unsigned char* __restrict__ KVb,
    const unsigned char* __restrict__ Sb,
    const int* __restrict__ offs, const int* __restrict__ bsums,
    const int* __restrict__ csr_src,
    float* __restrict__ out, unsigned short* __restrict__ Xb,
    int n, int Etot, int mode)
{
    int node = blockIdx.x * 4 + (threadIdx.x >> 6);
    if (node >= n) return;
    int lane = threadIdx.x & 63;
    int sl = lane & 31;
    int half = lane >> 5;
    uint2 q8 = *(const uint2*)(Qb + (size_t)node * 256 + sl * 8);
    int beg = offs[node] + bsums[node >> 11];
    int end = (node + 1 < n) ? (offs[node + 1] + bsums[(node + 1) >> 11]) : Etot;
    float l = 0.f;
    float acc[8];
#pragma unroll
    for (int i = 0; i < 8; ++i) acc[i] = 0.f;
    for (int base = beg; base < end; base += 8) {
        int cnt = end - base; if (cnt > 8) cnt = 8;
        int my = (lane < cnt) ? csr_src[base + lane] : 0;
        uint2 kk[4], vv[4];
#pragma unroll
        for (int p = 0; p < 4; ++p) {
            int idx = __shfl(my, 2 * p + half);
            const unsigned char* row = KVb + (size_t)idx * 512 + sl * 8;
            kk[p] = *(const uint2*)(row);
            vv[p] = *(const uint2*)(row + 256);
        }
#pragma unroll
        for (int p = 0; p < 4; ++p) {
            int d = sdot4(kk[p].x, q8.x, 0);
            d = sdot4(kk[p].y, q8.y, d);
            d += __shfl_xor(d, 1); d += __shfl_xor(d, 2); d += __shfl_xor(d, 4);
            float w = __builtin_exp2f((float)d * C_EXP2);
            w = (2 * p + half < cnt) ? w : 0.f;
            l += w;
            float4 va = fp8x4_unpack(vv[p].x);
            float4 vb = fp8x4_unpack(vv[p].y);
            acc[0] += va.x * w; acc[1] += va.y * w;
            acc[2] += va.z * w; acc[3] += va.w * w;
            acc[4] += vb.x * w; acc[5] += vb.y * w;
            acc[6] += vb.z * w; acc[7] += vb.w * w;
        }
    }
    l += __shfl_xor(l, 32);
#pragma unroll
    for (int i = 0; i < 8; ++i) acc[i] += __shfl_xor(acc[i], 32);
    float inv = 1.f / (l + 1e-16f);
#pragma unroll
    for (int i = 0; i < 8; ++i) acc[i] *= inv;
#pragma unroll
    for (int i = 0; i < 8; ++i) {
        acc[i] += __shfl_xor(acc[i], 8);
        acc[i] += __shfl_xor(acc[i], 16);
        acc[i] *= 0.25f;
    }
    if (lane < 8) {
        const float* Srow = (const float*)(Sb + (size_t)node * 256);
        float4 s0 = *(const float4*)(Srow + lane * 8);
        float4 s1 = *(const float4*)(Srow + lane * 8 + 4);
        float r0 = acc[0] + s0.x, r1 = acc[1] + s0.y;
        float r2 = acc[2] + s0.z, r3 = acc[3] + s0.w;
        float r4 = acc[4] + s1.x, r5 = acc[5] + s1.y;
        float r6 = acc[6] + s1.z, r7 = acc[7] + s1.w;
        if (mode == 1) {
            r0 = fmaxf(r0, 0.f); r1 = fmaxf(r1, 0.f);
            r2 = fmaxf(r2, 0.f); r3 = fmaxf(r3, 0.f);
            r4 = fmaxf(r4, 0.f); r5 = fmaxf(r5, 0.f);
            r6 = fmaxf(r6, 0.f); r7 = fmaxf(r7, 0.f);
            uint4 o;
            o.x = (unsigned int)f2bf(r0) | ((unsigned int)f2bf(r1) << 16);
            o.y = (unsigned int)f2bf(r2) | ((unsigned int)f2bf(r3) << 16);
            o.z = (unsigned int)f2bf(r4) | ((unsigned int)f2bf(r5) << 16);
            o.w = (unsigned int)f2bf(r6) | ((unsigned int)f2bf(r7) << 16);
            *(uint4*)(Xb + (size_t)node * 64 + lane * 8) = o;
        } else {
            *(float4*)(out + (size_t)node * 64 + lane * 8) = make_float4(r0, r1, r2, r3);
            *(float4*)(out + (size_t)node * 64 + lane * 8 + 4) = make_float4(r4, r5, r6, r7);
        }
    }
}

extern "C" void kernel_launch(void* const* d_in, const int* in_sizes, int n_in,
                              void* d_out, int out_size, void* d_ws, size_t ws_size,
                              hipStream_t stream)
{
    const float* x  = (const float*)d_in[0];
    const int*   ei = (const int*)d_in[1];
    int N = in_sizes[0] / 64;
    int E = in_sizes[1] / 2;
    const int* srcp = ei;
    const int* dstp = ei + E;
    const float* Wq1 = (const float*)d_in[2],  *bq1 = (const float*)d_in[3];
    const float* Wk1 = (const float*)d_in[4],  *bk1 = (const float*)d_in[5];
    const float* Wv1 = (const float*)d_in[6],  *bv1 = (const float*)d_in[7];
    const float* Ws1 = (const float*)d_in[8],  *bs1 = (const float*)d_in[9];
    const float* Wq2 = (const float*)d_in[10], *bq2 = (const float*)d_in[11];
    const float* Wk2 = (const float*)d_in[12], *bk2 = (const float*)d_in[13];
    const float* Wv2 = (const float*)d_in[14], *bv2 = (const float*)d_in[15];
    const float* Ws2 = (const float*)d_in[16], *bs2 = (const float*)d_in[17];
    float* out = (float*)d_out;

    // workspace layout (~133 MB)
    char* ws = (char*)d_ws;
    size_t off = 0;
    auto alloc = [&](size_t bytes) -> void* {
        void* p = ws + off;
        off = (off + bytes + 255) & ~(size_t)255;
        return p;
    };
    unsigned short* Xb = (unsigned short*)alloc((size_t)N * 64 * 2);
    unsigned char* Qb  = (unsigned char*)alloc(((size_t)N + 64) * 256);
    unsigned char* KVb = (unsigned char*)alloc(((size_t)N + 64) * 512);
    unsigned char* Sb  = (unsigned char*)alloc(((size_t)N + 64) * 256);
    unsigned short* Wt = (unsigned short*)alloc(2 * 53248 * 2);
    int* counts = (int*)alloc((size_t)N * 4);
    int* rank   = (int*)alloc((size_t)E * 4);
    int* offs   = (int*)alloc((size_t)N * 4);
    int* bsums  = (int*)alloc(1024 * 4);
    int* csr    = (int*)alloc((size_t)E * 4);
    (void)n_in; (void)out_size;
    if (off > ws_size) return;  // diagnostic: too-small ws -> zeros, not a fault

    int ebl = (E + 255) / 256;
    int nb_scan = (N + SCAN_CHUNK - 1) / SCAN_CHUNK;
    int row_bl = (N + 63) / 64;
    int attn_bl = (N + 3) / 4;
    int ncast4 = N * 16;
    int castBl = (ncast4 + 255) / 256;
    int zeroBl = (N + 255) / 256;

    // 1. setup: cast X, prep weights, zero counts
    k_setup<<<castBl + 416 + zeroBl, 256, 0, stream>>>(
        x, Xb, ncast4, Wq1, Wk1, Wv1, Ws1, Wq2, Wk2, Wv2, Ws2, Wt, counts, N, castBl);

    // 2. layer-1 GEMM + fused hist (independent block ranges)
    k_gemm<<<row_bl + ebl, 256, 0, stream>>>(
        Xb, N, Wt, bq1, bk1, bv1, bs1, Qb, KVb, Sb,
        dstp, E, counts, rank, row_bl);

    // 3-5. CSR: scan, scan2, atomic-free scatter
    k_scan1<<<nb_scan, SCAN_B, 0, stream>>>(counts, N, offs, bsums);
    k_scan2<<<1, 256, 0, stream>>>(bsums, nb_scan);
    k_scatter<<<ebl, 256, 0, stream>>>(srcp, dstp, E, offs, bsums, rank, csr);

    // 6. layer-1 attention (h1 -> Xb bf16)
    k_attn<<<attn_bl, 256, 0, stream>>>(Qb, KVb, Sb, offs, bsums, csr, out, Xb, N, E, 1);

    // 7. layer-2 GEMM (no hist blocks)
    k_gemm<<<row_bl, 256, 0, stream>>>(
        Xb, N, Wt + 53248, bq2, bk2, bv2, bs2, Qb, KVb, Sb,
        dstp, 0, counts, rank, row_bl);

    // 8. layer-2 attention
    k_attn<<<attn_bl, 256, 0, stream>>>(Qb, KVb, Sb, offs, bsums, csr, out, Xb, N, E, 0);
}